// Round 14
// baseline (223.019 us; speedup 1.0000x reference)
//
#include <hip/hip_runtime.h>
#include <hip/hip_bf16.h>

// ---------------------------------------------------------------------------
// GCN 2-layer + mean-pool + linear head. bf16 MFMA GEMMs (f32 accumulate),
// bf16 row-major intermediates, fixed-capacity binned CSR build (128-node
// buckets), 16-lane-per-node pull aggregation.
//   CSR: partition (fixed-cap buckets, 8K tiles) -> bucket_finalize
//   wconv: W transpose->bf16 both layers + bcur init + ps zero (1 launch)
//   gemm_mfma: hs1 = bf16((x @ W1) * dinv[row])
//   agg1_gemm2: r1 = relu(dinv*(sum hs1 + self) + b1) [f32, in LDS]
//               -> hs2 = bf16((r1 @ W2) * dinv)   (block-local MFMA, W2 L2-hot)
//   agg_pool:  relu(dinv*(sum hs2 + self) + b2) -> batch-run LDS reduce -> ps
//   final: out[g] = (ps[g].Wlin)/cnt(g) + blin   (cnt via binary search)
// ---------------------------------------------------------------------------

#define NBS 7
#define NPB 128          // nodes per bucket
#define PART_TILE 8192
#define BCAP 3072        // bucket capacity (mean 2046, sigma ~45 -> +23 sigma)

typedef __attribute__((ext_vector_type(8))) short short8;
typedef __attribute__((ext_vector_type(4))) float f32x4;

__device__ __forceinline__ float bf2f(unsigned short u) {
    return __uint_as_float(((unsigned int)u) << 16);
}
__device__ __forceinline__ unsigned short f2bf(float f) {
    unsigned int u = __float_as_uint(f);
    return (unsigned short)((u + 0x7FFFu + ((u >> 16) & 1u)) >> 16);
}
__device__ __forceinline__ short8 pack_bf8(f32x4 a, f32x4 b) {
    short8 s;
    s[0] = (short)f2bf(a.x); s[1] = (short)f2bf(a.y);
    s[2] = (short)f2bf(a.z); s[3] = (short)f2bf(a.w);
    s[4] = (short)f2bf(b.x); s[5] = (short)f2bf(b.y);
    s[6] = (short)f2bf(b.z); s[7] = (short)f2bf(b.w);
    return s;
}
__device__ __forceinline__ void acc8(int4 v, float* a) {
    a[0] += __uint_as_float(((unsigned int)v.x) << 16);
    a[1] += __uint_as_float(((unsigned int)v.x) & 0xFFFF0000u);
    a[2] += __uint_as_float(((unsigned int)v.y) << 16);
    a[3] += __uint_as_float(((unsigned int)v.y) & 0xFFFF0000u);
    a[4] += __uint_as_float(((unsigned int)v.z) << 16);
    a[5] += __uint_as_float(((unsigned int)v.z) & 0xFFFF0000u);
    a[6] += __uint_as_float(((unsigned int)v.w) << 16);
    a[7] += __uint_as_float(((unsigned int)v.w) & 0xFFFF0000u);
}
__device__ __forceinline__ unsigned int pack2(float x, float y) {
    return (unsigned int)f2bf(x) | ((unsigned int)f2bf(y) << 16);
}

// shared gather body: a[8] += sum of neighbor rows (+self), then bias+relu
__device__ __forceinline__ void gather_relu(const unsigned short* __restrict__ hs,
                                            const float* __restrict__ dinv,
                                            const int* __restrict__ rps,
                                            const int* __restrict__ rpe,
                                            const int* __restrict__ col,
                                            const float* __restrict__ bias,
                                            int g, int l, float* a) {
    const int4* h4 = (const int4*)hs;
    acc8(h4[(size_t)g * 16 + l], a);  // self (hs_i)
    int e = rps[g], end = rpe[g];
    for (; e + 7 < end; e += 8) {
        int j0 = col[e + 0], j1 = col[e + 1], j2 = col[e + 2], j3 = col[e + 3];
        int j4 = col[e + 4], j5 = col[e + 5], j6 = col[e + 6], j7 = col[e + 7];
        int4 v0 = h4[(size_t)j0 * 16 + l];
        int4 v1 = h4[(size_t)j1 * 16 + l];
        int4 v2 = h4[(size_t)j2 * 16 + l];
        int4 v3 = h4[(size_t)j3 * 16 + l];
        int4 v4 = h4[(size_t)j4 * 16 + l];
        int4 v5 = h4[(size_t)j5 * 16 + l];
        int4 v6 = h4[(size_t)j6 * 16 + l];
        int4 v7 = h4[(size_t)j7 * 16 + l];
        acc8(v0, a); acc8(v1, a); acc8(v2, a); acc8(v3, a);
        acc8(v4, a); acc8(v5, a); acc8(v6, a); acc8(v7, a);
    }
    for (; e + 1 < end; e += 2) {
        int j0 = col[e], j1 = col[e + 1];
        int4 v0 = h4[(size_t)j0 * 16 + l];
        int4 v1 = h4[(size_t)j1 * 16 + l];
        acc8(v0, a); acc8(v1, a);
    }
    if (e < end) acc8(h4[(size_t)col[e] * 16 + l], a);

    float dv = dinv[g];
    float4 b0 = ((const float4*)bias)[l * 2];
    float4 b1 = ((const float4*)bias)[l * 2 + 1];
    a[0] = fmaxf(fmaf(a[0], dv, b0.x), 0.f);
    a[1] = fmaxf(fmaf(a[1], dv, b0.y), 0.f);
    a[2] = fmaxf(fmaf(a[2], dv, b0.z), 0.f);
    a[3] = fmaxf(fmaf(a[3], dv, b0.w), 0.f);
    a[4] = fmaxf(fmaf(a[4], dv, b1.x), 0.f);
    a[5] = fmaxf(fmaf(a[5], dv, b1.y), 0.f);
    a[6] = fmaxf(fmaf(a[6], dv, b1.z), 0.f);
    a[7] = fmaxf(fmaf(a[7], dv, b1.w), 0.f);
}

// ---------------- CSR build (fixed-capacity buckets) ----------------

__global__ __launch_bounds__(256) void partition_kernel(const int* __restrict__ src,
                                                        const int* __restrict__ dst, int E,
                                                        int* __restrict__ bcur,
                                                        unsigned int* __restrict__ pairs,
                                                        int B) {
    __shared__ int h[1024];
    __shared__ int rankbase[1024];
    int t = threadIdx.x;
    int tile0 = blockIdx.x * PART_TILE;

    for (int half = 0; half < 2; ++half) {
        for (int i = t; i < B; i += 256) h[i] = 0;
        __syncthreads();
        int base0 = tile0 + half * 4096;
        int bk[16];
        int rk[16];
        unsigned int pk[16];
#pragma unroll
        for (int j = 0; j < 16; ++j) {
            int idx = base0 + j * 256 + t;
            bk[j] = -1;
            if (idx < E) {
                int d = dst[idx];
                int s = src[idx];
                bk[j] = d >> NBS;
                pk[j] = ((unsigned int)(d & (NPB - 1)) << 23) | (unsigned int)s;
                rk[j] = atomicAdd(&h[bk[j]], 1);
            }
        }
        __syncthreads();
        for (int i = t; i < B; i += 256) rankbase[i] = h[i] ? atomicAdd(&bcur[i], h[i]) : 0;
        __syncthreads();
#pragma unroll
        for (int j = 0; j < 16; ++j)
            if (bk[j] >= 0) pairs[rankbase[bk[j]] + rk[j]] = pk[j];
        __syncthreads();
    }
}

// per-bucket: hist + in-bucket scan -> rps/rpe/dinv + scatter -> col
__global__ __launch_bounds__(256) void bucket_finalize(const unsigned int* __restrict__ pairs,
                                                       const int* __restrict__ bcur,
                                                       int* __restrict__ rps,
                                                       int* __restrict__ rpe,
                                                       float* __restrict__ dinv,
                                                       int* __restrict__ col, int N) {
    __shared__ int c[NPB];
    __shared__ int sa[NPB];
    __shared__ int sb[NPB];
    __shared__ unsigned int stage[BCAP];
    int b = blockIdx.x;
    int s = b * BCAP;
    int cnt = bcur[b] - s;
    if (threadIdx.x < NPB) c[threadIdx.x] = 0;
    __syncthreads();
    for (int i = threadIdx.x; i < cnt; i += 256) {
        unsigned int p = pairs[s + i];
        stage[i] = p;
        atomicAdd(&c[p >> 23], 1);
    }
    __syncthreads();
    if (threadIdx.x < NPB) sa[threadIdx.x] = c[threadIdx.x];
    __syncthreads();
    int* pin = sa;
    int* pout = sb;
    for (int off = 1; off < NPB; off <<= 1) {
        if (threadIdx.x < NPB)
            pout[threadIdx.x] = pin[threadIdx.x] + ((threadIdx.x >= (unsigned)off) ? pin[threadIdx.x - off] : 0);
        __syncthreads();
        int* tmp = pin; pin = pout; pout = tmp;
    }
    int base = b << NBS;
    if (threadIdx.x < NPB) {
        int i = threadIdx.x;
        int excl = s + pin[i] - c[i];
        pout[i] = excl;
        int node = base + i;
        if (node < N) {
            rps[node] = excl;
            rpe[node] = excl + c[i];
            dinv[node] = rsqrtf((float)c[i] + 1.0f);
        }
    }
    __syncthreads();
    for (int i = threadIdx.x; i < cnt; i += 256) {
        unsigned int p = stage[i];
        int dL = (int)(p >> 23);
        int pos = atomicAdd(&pout[dL], 1);
        col[pos] = (int)(p & 0x7FFFFFu);
    }
}

// ---------------- weight prep + bcur init + ps zero (one launch) ----------------

__global__ void wconv_kernel(const float* __restrict__ W1, const float* __restrict__ W2,
                             unsigned short* __restrict__ Wt1, unsigned short* __restrict__ Wt2,
                             int* __restrict__ bcur, int B,
                             float* __restrict__ ps, int psn) {
    const float* W = (blockIdx.x & 128) ? W2 : W1;
    unsigned short* Wt = (blockIdx.x & 128) ? Wt2 : Wt1;
    int n = blockIdx.x & 127;
    int k = threadIdx.x;
    Wt[n * 128 + k] = f2bf(W[k * 128 + n]);
    int tid = blockIdx.x * 128 + threadIdx.x;
    if (tid < B) bcur[tid] = tid * BCAP;
    for (int i = tid; i < psn; i += 256 * 128) ps[i] = 0.f;
}

// ---------------- GEMM (MFMA): hs1 = bf16((x @ W1) * dinv) ----------------

__global__ __launch_bounds__(256) void gemm_mfma(const float* __restrict__ A,
                                                 const unsigned short* __restrict__ Wt,
                                                 const float* __restrict__ dinv,
                                                 unsigned short* __restrict__ C, int M) {
    __shared__ unsigned char lds[32768];
    int t = threadIdx.x;
#pragma unroll
    for (int i = 0; i < 8; ++i) {
        int c = t + i * 256;
        int row = c >> 4;
        int b = (c & 15) << 4;
        int4 v = ((const int4*)Wt)[c];
        *(int4*)&lds[row * 256 + (b ^ ((row & 7) << 4))] = v;
    }

    int lane = t & 63;
    int wv = t >> 6;
    int r0 = blockIdx.x * 64 + wv * 16;
    int l15 = lane & 15;
    int kg = lane >> 4;

    short8 af[4];
    {
        int row = r0 + l15;
        row = row < M ? row : M - 1;
#pragma unroll
        for (int kk = 0; kk < 4; ++kk) {
            size_t eoff = (size_t)row * 128 + kk * 32 + kg * 8;
            f32x4 v0 = __builtin_nontemporal_load((const f32x4*)(A + eoff));
            f32x4 v1 = __builtin_nontemporal_load((const f32x4*)(A + eoff + 4));
            af[kk] = pack_bf8(v0, v1);
        }
    }
    __syncthreads();

    f32x4 acc[8];
#pragma unroll
    for (int cf = 0; cf < 8; ++cf) acc[cf] = (f32x4)(0.f);

#pragma unroll
    for (int cf = 0; cf < 8; ++cf) {
        short8 bfr[4];
#pragma unroll
        for (int kk = 0; kk < 4; ++kk) {
            int brow = cf * 16 + l15;
            int bb = kk * 64 + kg * 16;
            bfr[kk] = *(const short8*)&lds[brow * 256 + (bb ^ ((brow & 7) << 4))];
        }
#pragma unroll
        for (int kk = 0; kk < 4; ++kk)
            acc[cf] = __builtin_amdgcn_mfma_f32_16x16x32_bf16(af[kk], bfr[kk], acc[cf], 0, 0, 0);
    }

#pragma unroll
    for (int r = 0; r < 4; ++r) {
        int row = r0 + kg * 4 + r;
        if (row < M) {
            float dv = dinv[row];
#pragma unroll
            for (int cf = 0; cf < 8; ++cf)
                C[(size_t)row * 128 + cf * 16 + l15] = f2bf(acc[cf][r] * dv);
        }
    }
}

// ---- fused: agg layer1 (r1 in LDS, bf16) + block-local GEMM2 -> hs2 ----

__global__ __launch_bounds__(256) void agg1_gemm2(const unsigned short* __restrict__ hs,
                                                  const float* __restrict__ dinv,
                                                  const int* __restrict__ rps,
                                                  const int* __restrict__ rpe,
                                                  const int* __restrict__ col,
                                                  const float* __restrict__ b1,
                                                  const unsigned short* __restrict__ Wt2,
                                                  unsigned short* __restrict__ hs2, int N) {
    __shared__ unsigned char sacc[16 * 256];  // r1 rows, bf16, XOR-swizzled
    int slot = threadIdx.x >> 4;
    int g = blockIdx.x * 16 + slot;
    int l = threadIdx.x & 15;
    bool valid = (g < N);

    float a[8];
#pragma unroll
    for (int k = 0; k < 8; ++k) a[k] = 0.f;
    if (valid) gather_relu(hs, dinv, rps, rpe, col, b1, g, l, a);

    // write r1 row (bf16) to LDS, swizzled like gemm's Wt
    int4 o;
    o.x = (int)pack2(a[0], a[1]);
    o.y = (int)pack2(a[2], a[3]);
    o.z = (int)pack2(a[4], a[5]);
    o.w = (int)pack2(a[6], a[7]);
    *(int4*)&sacc[slot * 256 + ((l * 16) ^ ((slot & 7) << 4))] = o;
    __syncthreads();

    // MFMA: 16 rows (block nodes) x 128 cols; wave wv does cf = 2*wv, 2*wv+1
    int lane = threadIdx.x & 63;
    int wv = threadIdx.x >> 6;
    int l15 = lane & 15;
    int kg = lane >> 4;

    short8 af[4];
#pragma unroll
    for (int kk = 0; kk < 4; ++kk) {
        int bb = kk * 64 + kg * 16;
        af[kk] = *(const short8*)&sacc[l15 * 256 + (bb ^ ((l15 & 7) << 4))];
    }

#pragma unroll
    for (int c2 = 0; c2 < 2; ++c2) {
        int cf = wv * 2 + c2;
        f32x4 acc = (f32x4)(0.f);
#pragma unroll
        for (int kk = 0; kk < 4; ++kk) {
            short8 bfr = *(const short8*)&Wt2[(size_t)(cf * 16 + l15) * 128 + kk * 32 + kg * 8];
            acc = __builtin_amdgcn_mfma_f32_16x16x32_bf16(af[kk], bfr, acc, 0, 0, 0);
        }
#pragma unroll
        for (int r = 0; r < 4; ++r) {
            int row = blockIdx.x * 16 + kg * 4 + r;
            if (row < N)
                hs2[(size_t)row * 128 + cf * 16 + l15] = f2bf(acc[r] * dinv[row]);
        }
    }
}

// ---- agg layer2 + fused mean-pool accumulation ----

__global__ __launch_bounds__(256) void agg_pool(const unsigned short* __restrict__ hs,
                                                const float* __restrict__ dinv,
                                                const int* __restrict__ rps,
                                                const int* __restrict__ rpe,
                                                const int* __restrict__ col,
                                                const float* __restrict__ bias,
                                                const int* __restrict__ batch,
                                                float* __restrict__ ps, int N) {
    __shared__ float sacc[16][128];
    __shared__ int sbatch[16];
    int slot = threadIdx.x >> 4;
    int g = blockIdx.x * 16 + slot;
    int l = threadIdx.x & 15;
    bool valid = (g < N);

    float a[8];
#pragma unroll
    for (int k = 0; k < 8; ++k) a[k] = 0.f;
    if (valid) gather_relu(hs, dinv, rps, rpe, col, bias, g, l, a);

    if (l == 0) sbatch[slot] = valid ? batch[g] : -1;
#pragma unroll
    for (int k = 0; k < 8; ++k) sacc[slot][l * 8 + k] = a[k];
    __syncthreads();
    if (threadIdx.x < 128) {
        int f = threadIdx.x;
        float run = 0.f;
        int curg = sbatch[0];
#pragma unroll
        for (int s2 = 0; s2 < 16; ++s2) {
            int gg = sbatch[s2];
            if (gg < 0) break;
            if (gg != curg) {
                atomicAdd(&ps[curg * 128 + f], run);
                run = 0.f;
                curg = gg;
            }
            run += sacc[s2][f];
        }
        if (curg >= 0) atomicAdd(&ps[curg * 128 + f], run);
    }
}

// out[g] = (ps[g] . Wlin) / cnt(g) + blin; cnt via binary search on sorted batch
__global__ __launch_bounds__(256) void final_kernel(const float* __restrict__ ps,
                                                    const int* __restrict__ batch, int N,
                                                    const float* __restrict__ Wlin,
                                                    const float* __restrict__ blin,
                                                    float* __restrict__ out, int G) {
    int g = (int)((blockIdx.x * 256 + threadIdx.x) >> 6);
    int lane = threadIdx.x & 63;
    if (g >= G) return;
    float2 s = ((const float2*)ps)[g * 64 + lane];
    float2 w = ((const float2*)Wlin)[lane];
    float v = s.x * w.x + s.y * w.y;
#pragma unroll
    for (int off = 32; off > 0; off >>= 1) v += __shfl_down(v, off);
    if (lane == 0) {
        int lo = 0, hi = N;
        while (lo < hi) { int m = (lo + hi) >> 1; if (batch[m] < g) lo = m + 1; else hi = m; }
        int lb = lo;
        hi = N;
        while (lo < hi) { int m = (lo + hi) >> 1; if (batch[m] <= g) lo = m + 1; else hi = m; }
        float c = (float)max(lo - lb, 1);
        out[g] = v / c + blin[0];
    }
}

extern "C" void kernel_launch(void* const* d_in, const int* in_sizes, int n_in,
                              void* d_out, int out_size, void* d_ws, size_t ws_size,
                              hipStream_t stream) {
    const float* x    = (const float*)d_in[0];
    const float* W1   = (const float*)d_in[1];
    const float* b1   = (const float*)d_in[2];
    const float* W2   = (const float*)d_in[3];
    const float* b2   = (const float*)d_in[4];
    const float* Wlin = (const float*)d_in[5];
    const float* blin = (const float*)d_in[6];
    const int*   ei   = (const int*)d_in[7];   // [2, E]
    const int*   batch= (const int*)d_in[8];   // [N]

    const int N = in_sizes[0] / 128;
    const int E = in_sizes[7] / 2;
    const int G = out_size;
    const int B = (N + NPB - 1) >> NBS;

    const int* srcp = ei;
    const int* dstp = ei + E;

    char* w = (char*)d_ws;
    size_t off = 0;
    auto carve = [&](size_t bytes) {
        size_t o = off;
        off = (off + bytes + 255) & ~(size_t)255;
        return (void*)(w + o);
    };
    unsigned short* bufA = (unsigned short*)carve((size_t)N * 128 * 2);  // hs1
    unsigned short* bufB = (unsigned short*)carve((size_t)N * 128 * 2);  // hs2
    float* dinv = (float*)carve((size_t)N * 4);
    int*   rps  = (int*)carve((size_t)N * 4);
    int*   rpe  = (int*)carve((size_t)N * 4);
    int*   col  = (int*)carve((size_t)B * BCAP * 4);
    unsigned int* pairs = (unsigned int*)carve((size_t)B * BCAP * 4);
    int*   bcur = (int*)carve((size_t)(B + 1) * 4);
    unsigned short* Wt1 = (unsigned short*)carve(128 * 128 * 2);
    unsigned short* Wt2 = (unsigned short*)carve(128 * 128 * 2);
    float* ps   = (float*)carve((size_t)G * 128 * 4);
    (void)ws_size;

    const int ntiles = (E + PART_TILE - 1) / PART_TILE;

    // weight prep + bcur init + ps zero (must precede partition & agg_pool)
    wconv_kernel<<<256, 128, 0, stream>>>(W1, W2, Wt1, Wt2, bcur, B, ps, G * 128);

    // CSR build (fixed-capacity buckets; no count/scan passes)
    partition_kernel<<<ntiles, 256, 0, stream>>>(srcp, dstp, E, bcur, pairs, B);
    bucket_finalize<<<B, 256, 0, stream>>>(pairs, bcur, rps, rpe, dinv, col, N);

    const int gemm_grid = (N + 63) / 64;
    const int agg_grid  = (N + 15) / 16;

    // layer 1 GEMM
    gemm_mfma<<<gemm_grid, 256, 0, stream>>>(x, Wt1, dinv, bufA, N);
    // layer-1 aggregation fused with layer-2 GEMM
    agg1_gemm2<<<agg_grid, 256, 0, stream>>>(bufA, dinv, rps, rpe, col, b1, Wt2, bufB, N);
    // layer-2 aggregation + fused mean-pool accumulation
    agg_pool<<<agg_grid, 256, 0, stream>>>(bufB, dinv, rps, rpe, col, b2, batch, ps, N);

    // head
    final_kernel<<<(G * 64 + 255) / 256, 256, 0, stream>>>(ps, batch, N, Wlin, blin,
                                                           (float*)d_out, G);
}

// Round 15
// 218.802 us; speedup vs baseline: 1.0193x; 1.0193x over previous
//
#include <hip/hip_runtime.h>
#include <hip/hip_bf16.h>

// ---------------------------------------------------------------------------
// GCN 2-layer + mean-pool + linear head. bf16 MFMA GEMMs (f32 accumulate),
// bf16 row-major intermediates, fixed-capacity binned CSR build (128-node
// buckets), 16-lane-per-node pull aggregation, pool fused into layer-2 agg.
//   memsets: bcur=0, ps=0 (DMA nodes)
//   partition (fixed-cap buckets, 8K tiles; +128 tail blocks do W->Wt bf16)
//   bucket_finalize: hist + in-bucket scan -> rps/rpe/dinv + scatter -> col
//   gemm_mfma: hs1 = bf16((x @ W1) * dinv[row])  [64-row blocks]
//   agg_q16<false>: r1 = bf16(relu(dinv*(sum hs1 + self) + b1))
//   gemm_mfma2: hs2 = bf16((r1 @ W2) * dinv[row])
//   agg_q16<true>: relu(...) f32 -> batch-run LDS reduce -> atomicAdd ps
//   final: out[g] = (ps[g].Wlin)/cnt(g) + blin   (cnt via binary search)
// ---------------------------------------------------------------------------

#define NBS 7
#define NPB 128          // nodes per bucket
#define PART_TILE 8192
#define BCAP 3072        // bucket capacity (mean 2046, sigma ~45 -> +23 sigma)

typedef __attribute__((ext_vector_type(8))) short short8;
typedef __attribute__((ext_vector_type(4))) float f32x4;

__device__ __forceinline__ float bf2f(unsigned short u) {
    return __uint_as_float(((unsigned int)u) << 16);
}
__device__ __forceinline__ unsigned short f2bf(float f) {
    unsigned int u = __float_as_uint(f);
    return (unsigned short)((u + 0x7FFFu + ((u >> 16) & 1u)) >> 16);
}
__device__ __forceinline__ short8 pack_bf8(f32x4 a, f32x4 b) {
    short8 s;
    s[0] = (short)f2bf(a.x); s[1] = (short)f2bf(a.y);
    s[2] = (short)f2bf(a.z); s[3] = (short)f2bf(a.w);
    s[4] = (short)f2bf(b.x); s[5] = (short)f2bf(b.y);
    s[6] = (short)f2bf(b.z); s[7] = (short)f2bf(b.w);
    return s;
}
__device__ __forceinline__ void acc8(int4 v, float* a) {
    a[0] += __uint_as_float(((unsigned int)v.x) << 16);
    a[1] += __uint_as_float(((unsigned int)v.x) & 0xFFFF0000u);
    a[2] += __uint_as_float(((unsigned int)v.y) << 16);
    a[3] += __uint_as_float(((unsigned int)v.y) & 0xFFFF0000u);
    a[4] += __uint_as_float(((unsigned int)v.z) << 16);
    a[5] += __uint_as_float(((unsigned int)v.z) & 0xFFFF0000u);
    a[6] += __uint_as_float(((unsigned int)v.w) << 16);
    a[7] += __uint_as_float(((unsigned int)v.w) & 0xFFFF0000u);
}
__device__ __forceinline__ unsigned int pack2(float x, float y) {
    return (unsigned int)f2bf(x) | ((unsigned int)f2bf(y) << 16);
}

// ---------------- CSR build (fixed-capacity buckets) + weight prep ----------------

// blocks [0, ntiles): edge partition. blocks [ntiles, ntiles+128): W->Wt bf16.
__global__ __launch_bounds__(256) void partition_kernel(const int* __restrict__ src,
                                                        const int* __restrict__ dst, int E,
                                                        int* __restrict__ bcur,
                                                        unsigned int* __restrict__ pairs,
                                                        int B, int ntiles,
                                                        const float* __restrict__ W1,
                                                        const float* __restrict__ W2,
                                                        unsigned short* __restrict__ Wt1,
                                                        unsigned short* __restrict__ Wt2) {
    if (blockIdx.x >= ntiles) {
        // weight transpose+convert: 128 blocks x 256 thr = 2 x 128 x 128
        int wb = blockIdx.x - ntiles;           // 0..127
        const float* W = (wb & 64) ? W2 : W1;
        unsigned short* Wt = (wb & 64) ? Wt2 : Wt1;
        int n = ((wb & 63) << 1) | (threadIdx.x >> 7);  // 0..127
        int k = threadIdx.x & 127;
        Wt[n * 128 + k] = f2bf(W[k * 128 + n]);
        return;
    }
    __shared__ int h[1024];
    __shared__ int rankbase[1024];
    int t = threadIdx.x;
    int tile0 = blockIdx.x * PART_TILE;

    for (int half = 0; half < 2; ++half) {
        for (int i = t; i < B; i += 256) h[i] = 0;
        __syncthreads();
        int base0 = tile0 + half * 4096;
        int bk[16];
        int rk[16];
        unsigned int pk[16];
#pragma unroll
        for (int j = 0; j < 16; ++j) {
            int idx = base0 + j * 256 + t;
            bk[j] = -1;
            if (idx < E) {
                int d = dst[idx];
                int s = src[idx];
                bk[j] = d >> NBS;
                pk[j] = ((unsigned int)(d & (NPB - 1)) << 23) | (unsigned int)s;
                rk[j] = atomicAdd(&h[bk[j]], 1);
            }
        }
        __syncthreads();
        for (int i = t; i < B; i += 256)
            rankbase[i] = h[i] ? (i * BCAP + atomicAdd(&bcur[i], h[i])) : 0;
        __syncthreads();
#pragma unroll
        for (int j = 0; j < 16; ++j)
            if (bk[j] >= 0) pairs[rankbase[bk[j]] + rk[j]] = pk[j];
        __syncthreads();
    }
}

// per-bucket: hist + in-bucket scan -> rps/rpe/dinv + scatter -> col
__global__ __launch_bounds__(256) void bucket_finalize(const unsigned int* __restrict__ pairs,
                                                       const int* __restrict__ bcur,
                                                       int* __restrict__ rps,
                                                       int* __restrict__ rpe,
                                                       float* __restrict__ dinv,
                                                       int* __restrict__ col, int N) {
    __shared__ int c[NPB];
    __shared__ int sa[NPB];
    __shared__ int sb[NPB];
    __shared__ unsigned int stage[BCAP];
    int b = blockIdx.x;
    int s = b * BCAP;
    int cnt = bcur[b];          // count only (offsets were bucket-relative)
    if (threadIdx.x < NPB) c[threadIdx.x] = 0;
    __syncthreads();
    for (int i = threadIdx.x; i < cnt; i += 256) {
        unsigned int p = pairs[s + i];
        stage[i] = p;
        atomicAdd(&c[p >> 23], 1);
    }
    __syncthreads();
    if (threadIdx.x < NPB) sa[threadIdx.x] = c[threadIdx.x];
    __syncthreads();
    int* pin = sa;
    int* pout = sb;
    for (int off = 1; off < NPB; off <<= 1) {
        if (threadIdx.x < NPB)
            pout[threadIdx.x] = pin[threadIdx.x] + ((threadIdx.x >= (unsigned)off) ? pin[threadIdx.x - off] : 0);
        __syncthreads();
        int* tmp = pin; pin = pout; pout = tmp;
    }
    int base = b << NBS;
    if (threadIdx.x < NPB) {
        int i = threadIdx.x;
        int excl = s + pin[i] - c[i];
        pout[i] = excl;
        int node = base + i;
        if (node < N) {
            rps[node] = excl;
            rpe[node] = excl + c[i];
            dinv[node] = rsqrtf((float)c[i] + 1.0f);
        }
    }
    __syncthreads();
    for (int i = threadIdx.x; i < cnt; i += 256) {
        unsigned int p = stage[i];
        int dL = (int)(p >> 23);
        int pos = atomicAdd(&pout[dL], 1);
        col[pos] = (int)(p & 0x7FFFFFu);
    }
}

// shared gather body: a[8] += sum of neighbor rows (+self), then bias+relu
__device__ __forceinline__ void gather_relu(const unsigned short* __restrict__ hs,
                                            const float* __restrict__ dinv,
                                            const int* __restrict__ rps,
                                            const int* __restrict__ rpe,
                                            const int* __restrict__ col,
                                            const float* __restrict__ bias,
                                            int g, int l, float* a) {
    const int4* h4 = (const int4*)hs;
    acc8(h4[(size_t)g * 16 + l], a);  // self (hs_i)
    int e = rps[g], end = rpe[g];
    for (; e + 7 < end; e += 8) {
        int j0 = col[e + 0], j1 = col[e + 1], j2 = col[e + 2], j3 = col[e + 3];
        int j4 = col[e + 4], j5 = col[e + 5], j6 = col[e + 6], j7 = col[e + 7];
        int4 v0 = h4[(size_t)j0 * 16 + l];
        int4 v1 = h4[(size_t)j1 * 16 + l];
        int4 v2 = h4[(size_t)j2 * 16 + l];
        int4 v3 = h4[(size_t)j3 * 16 + l];
        int4 v4 = h4[(size_t)j4 * 16 + l];
        int4 v5 = h4[(size_t)j5 * 16 + l];
        int4 v6 = h4[(size_t)j6 * 16 + l];
        int4 v7 = h4[(size_t)j7 * 16 + l];
        acc8(v0, a); acc8(v1, a); acc8(v2, a); acc8(v3, a);
        acc8(v4, a); acc8(v5, a); acc8(v6, a); acc8(v7, a);
    }
    for (; e + 1 < end; e += 2) {
        int j0 = col[e], j1 = col[e + 1];
        int4 v0 = h4[(size_t)j0 * 16 + l];
        int4 v1 = h4[(size_t)j1 * 16 + l];
        acc8(v0, a); acc8(v1, a);
    }
    if (e < end) acc8(h4[(size_t)col[e] * 16 + l], a);

    float dv = dinv[g];
    float4 b0 = ((const float4*)bias)[l * 2];
    float4 b1 = ((const float4*)bias)[l * 2 + 1];
    a[0] = fmaxf(fmaf(a[0], dv, b0.x), 0.f);
    a[1] = fmaxf(fmaf(a[1], dv, b0.y), 0.f);
    a[2] = fmaxf(fmaf(a[2], dv, b0.z), 0.f);
    a[3] = fmaxf(fmaf(a[3], dv, b0.w), 0.f);
    a[4] = fmaxf(fmaf(a[4], dv, b1.x), 0.f);
    a[5] = fmaxf(fmaf(a[5], dv, b1.y), 0.f);
    a[6] = fmaxf(fmaf(a[6], dv, b1.z), 0.f);
    a[7] = fmaxf(fmaf(a[7], dv, b1.w), 0.f);
}

// ---------------- GEMM (MFMA) ----------------

// 64 rows/block, 4 waves x 16 rows. Wt (128x128 bf16) staged+swizzled in LDS.
template <bool A_F32>
__global__ __launch_bounds__(256) void gemm_mfma(const void* __restrict__ Ap,
                                                 const unsigned short* __restrict__ Wt,
                                                 const float* __restrict__ dinv,
                                                 unsigned short* __restrict__ C, int M) {
    __shared__ unsigned char lds[32768];
    int t = threadIdx.x;
#pragma unroll
    for (int i = 0; i < 8; ++i) {
        int c = t + i * 256;
        int row = c >> 4;
        int b = (c & 15) << 4;
        int4 v = ((const int4*)Wt)[c];
        *(int4*)&lds[row * 256 + (b ^ ((row & 7) << 4))] = v;
    }

    int lane = t & 63;
    int wv = t >> 6;
    int r0 = blockIdx.x * 64 + wv * 16;
    int l15 = lane & 15;
    int kg = lane >> 4;

    short8 af[4];
    {
        int row = r0 + l15;
        row = row < M ? row : M - 1;
#pragma unroll
        for (int kk = 0; kk < 4; ++kk) {
            size_t eoff = (size_t)row * 128 + kk * 32 + kg * 8;
            if constexpr (A_F32) {
                const float* A = (const float*)Ap;
                f32x4 v0 = __builtin_nontemporal_load((const f32x4*)(A + eoff));
                f32x4 v1 = __builtin_nontemporal_load((const f32x4*)(A + eoff + 4));
                af[kk] = pack_bf8(v0, v1);
            } else {
                af[kk] = *(const short8*)((const unsigned short*)Ap + eoff);
            }
        }
    }
    __syncthreads();

    f32x4 acc[8];
#pragma unroll
    for (int cf = 0; cf < 8; ++cf) acc[cf] = (f32x4)(0.f);

#pragma unroll
    for (int cf = 0; cf < 8; ++cf) {
        short8 bfr[4];
#pragma unroll
        for (int kk = 0; kk < 4; ++kk) {
            int brow = cf * 16 + l15;
            int bb = kk * 64 + kg * 16;
            bfr[kk] = *(const short8*)&lds[brow * 256 + (bb ^ ((brow & 7) << 4))];
        }
#pragma unroll
        for (int kk = 0; kk < 4; ++kk)
            acc[cf] = __builtin_amdgcn_mfma_f32_16x16x32_bf16(af[kk], bfr[kk], acc[cf], 0, 0, 0);
    }

#pragma unroll
    for (int r = 0; r < 4; ++r) {
        int row = r0 + kg * 4 + r;
        if (row < M) {
            float dv = dinv[row];
#pragma unroll
            for (int cf = 0; cf < 8; ++cf)
                C[(size_t)row * 128 + cf * 16 + l15] = f2bf(acc[cf][r] * dv);
        }
    }
}

// ---------------- aggregation (+ fused pool for layer 2) ----------------

// 16 lanes/node (dwordx4 gathers), 16 nodes/block, natural node order.
template <bool FUSE_POOL>
__global__ __launch_bounds__(256) void agg_q16(const unsigned short* __restrict__ hs,
                                               const float* __restrict__ dinv,
                                               const int* __restrict__ rps,
                                               const int* __restrict__ rpe,
                                               const int* __restrict__ col,
                                               const float* __restrict__ bias,
                                               const int* __restrict__ batch,
                                               unsigned short* __restrict__ out,
                                               float* __restrict__ ps, int N) {
    int slot = threadIdx.x >> 4;
    int g = blockIdx.x * 16 + slot;
    int l = threadIdx.x & 15;
    bool valid = (g < N);
    if (!FUSE_POOL && !valid) return;

    float a[8];
#pragma unroll
    for (int k = 0; k < 8; ++k) a[k] = 0.f;
    if (valid) gather_relu(hs, dinv, rps, rpe, col, bias, g, l, a);

    if constexpr (FUSE_POOL) {
        __shared__ float sacc[16][128];
        __shared__ int sbatch[16];
        if (l == 0) sbatch[slot] = valid ? batch[g] : -1;
#pragma unroll
        for (int k = 0; k < 8; ++k) sacc[slot][l * 8 + k] = a[k];
        __syncthreads();
        if (threadIdx.x < 128) {
            int f = threadIdx.x;
            float run = 0.f;
            int curg = sbatch[0];
#pragma unroll
            for (int s2 = 0; s2 < 16; ++s2) {
                int gg = sbatch[s2];
                if (gg < 0) break;
                if (gg != curg) {
                    atomicAdd(&ps[curg * 128 + f], run);
                    run = 0.f;
                    curg = gg;
                }
                run += sacc[s2][f];
            }
            if (curg >= 0) atomicAdd(&ps[curg * 128 + f], run);
        }
    } else {
        int4 o;
        o.x = (int)pack2(a[0], a[1]);
        o.y = (int)pack2(a[2], a[3]);
        o.z = (int)pack2(a[4], a[5]);
        o.w = (int)pack2(a[6], a[7]);
        ((int4*)out)[(size_t)g * 16 + l] = o;
    }
}

// out[g] = (ps[g] . Wlin) / cnt(g) + blin; cnt via binary search on sorted batch
__global__ __launch_bounds__(256) void final_kernel(const float* __restrict__ ps,
                                                    const int* __restrict__ batch, int N,
                                                    const float* __restrict__ Wlin,
                                                    const float* __restrict__ blin,
                                                    float* __restrict__ out, int G) {
    int g = (int)((blockIdx.x * 256 + threadIdx.x) >> 6);
    int lane = threadIdx.x & 63;
    if (g >= G) return;
    float2 s = ((const float2*)ps)[g * 64 + lane];
    float2 w = ((const float2*)Wlin)[lane];
    float v = s.x * w.x + s.y * w.y;
#pragma unroll
    for (int off = 32; off > 0; off >>= 1) v += __shfl_down(v, off);
    if (lane == 0) {
        int lo = 0, hi = N;
        while (lo < hi) { int m = (lo + hi) >> 1; if (batch[m] < g) lo = m + 1; else hi = m; }
        int lb = lo;
        hi = N;
        while (lo < hi) { int m = (lo + hi) >> 1; if (batch[m] <= g) lo = m + 1; else hi = m; }
        float c = (float)max(lo - lb, 1);
        out[g] = v / c + blin[0];
    }
}

extern "C" void kernel_launch(void* const* d_in, const int* in_sizes, int n_in,
                              void* d_out, int out_size, void* d_ws, size_t ws_size,
                              hipStream_t stream) {
    const float* x    = (const float*)d_in[0];
    const float* W1   = (const float*)d_in[1];
    const float* b1   = (const float*)d_in[2];
    const float* W2   = (const float*)d_in[3];
    const float* b2   = (const float*)d_in[4];
    const float* Wlin = (const float*)d_in[5];
    const float* blin = (const float*)d_in[6];
    const int*   ei   = (const int*)d_in[7];   // [2, E]
    const int*   batch= (const int*)d_in[8];   // [N]

    const int N = in_sizes[0] / 128;
    const int E = in_sizes[7] / 2;
    const int G = out_size;
    const int B = (N + NPB - 1) >> NBS;

    const int* srcp = ei;
    const int* dstp = ei + E;

    char* w = (char*)d_ws;
    size_t off = 0;
    auto carve = [&](size_t bytes) {
        size_t o = off;
        off = (off + bytes + 255) & ~(size_t)255;
        return (void*)(w + o);
    };
    unsigned short* bufA = (unsigned short*)carve((size_t)N * 128 * 2);  // hs1 / hs2
    unsigned short* bufB = (unsigned short*)carve((size_t)N * 128 * 2);  // r1
    float* dinv = (float*)carve((size_t)N * 4);
    int*   rps  = (int*)carve((size_t)N * 4);
    int*   rpe  = (int*)carve((size_t)N * 4);
    int*   col  = (int*)carve((size_t)B * BCAP * 4);
    unsigned int* pairs = (unsigned int*)carve((size_t)B * BCAP * 4);
    int*   bcur = (int*)carve((size_t)(B + 1) * 4);
    unsigned short* Wt1 = (unsigned short*)carve(128 * 128 * 2);
    unsigned short* Wt2 = (unsigned short*)carve(128 * 128 * 2);
    float* ps   = (float*)carve((size_t)G * 128 * 4);
    (void)ws_size;

    const int ntiles = (E + PART_TILE - 1) / PART_TILE;

    // zero bucket cursors + pooled sums (DMA)
    hipMemsetAsync(bcur, 0, (size_t)(B + 1) * 4, stream);
    hipMemsetAsync(ps, 0, (size_t)G * 128 * 4, stream);

    // CSR partition (+ weight transpose/convert in 128 tail blocks)
    partition_kernel<<<ntiles + 128, 256, 0, stream>>>(srcp, dstp, E, bcur, pairs, B, ntiles,
                                                       W1, W2, Wt1, Wt2);
    bucket_finalize<<<B, 256, 0, stream>>>(pairs, bcur, rps, rpe, dinv, col, N);

    const int gemm_grid = (N + 63) / 64;
    const int agg_grid  = (N + 15) / 16;

    // layer 1
    gemm_mfma<true><<<gemm_grid, 256, 0, stream>>>(x, Wt1, dinv, bufA, N);
    agg_q16<false><<<agg_grid, 256, 0, stream>>>(bufA, dinv, rps, rpe, col, b1, batch, bufB, ps, N);
    // layer 2 (+ fused mean-pool accumulation)
    gemm_mfma<false><<<gemm_grid, 256, 0, stream>>>(bufB, Wt2, dinv, bufA, N);
    agg_q16<true><<<agg_grid, 256, 0, stream>>>(bufA, dinv, rps, rpe, col, b2, batch, bufB, ps, N);

    // head
    final_kernel<<<(G * 64 + 255) / 256, 256, 0, stream>>>(ps, batch, N, Wlin, blin,
                                                           (float*)d_out, G);
}

// Round 16
// 214.248 us; speedup vs baseline: 1.0409x; 1.0213x over previous
//
#include <hip/hip_runtime.h>
#include <hip/hip_bf16.h>

// ---------------------------------------------------------------------------
// GCN 2-layer + mean-pool + linear head. bf16 MFMA GEMMs (f32 accumulate),
// bf16 row-major intermediates, fixed-capacity binned CSR build (128-node
// buckets), 16-lane-per-node pull aggregation, pool fused into layer-2 agg.
//   CSR: partition (fixed-cap buckets) -> bucket_finalize
//        (hist + in-bucket scan -> rps/rpe/dinv + scatter -> col)
//   wconv: W transpose->bf16 for both layers + bcur init + ps zero (1 launch)
//   gemm_mfma: hs = bf16((A @ W) * dinv[row])   [64-row blocks, 16 rows/wave]
//   agg_q16<false>: r1 = bf16(relu(dinv*(sum hs + self) + b1))
//   agg_q16<true>:  f32 result -> batch-run LDS reduce -> atomicAdd ps
//   final: out[g] = (ps[g].Wlin)/cnt(g) + blin   (cnt via binary search)
// ---------------------------------------------------------------------------

#define NBS 7
#define NPB 128          // nodes per bucket
#define PART_TILE 4096
#define BCAP 3072        // bucket capacity (mean 2046, sigma ~45 -> +23 sigma)

typedef __attribute__((ext_vector_type(8))) short short8;
typedef __attribute__((ext_vector_type(4))) float f32x4;

__device__ __forceinline__ float bf2f(unsigned short u) {
    return __uint_as_float(((unsigned int)u) << 16);
}
__device__ __forceinline__ unsigned short f2bf(float f) {
    unsigned int u = __float_as_uint(f);
    return (unsigned short)((u + 0x7FFFu + ((u >> 16) & 1u)) >> 16);
}
__device__ __forceinline__ short8 pack_bf8(f32x4 a, f32x4 b) {
    short8 s;
    s[0] = (short)f2bf(a.x); s[1] = (short)f2bf(a.y);
    s[2] = (short)f2bf(a.z); s[3] = (short)f2bf(a.w);
    s[4] = (short)f2bf(b.x); s[5] = (short)f2bf(b.y);
    s[6] = (short)f2bf(b.z); s[7] = (short)f2bf(b.w);
    return s;
}
__device__ __forceinline__ void acc8(int4 v, float* a) {
    a[0] += __uint_as_float(((unsigned int)v.x) << 16);
    a[1] += __uint_as_float(((unsigned int)v.x) & 0xFFFF0000u);
    a[2] += __uint_as_float(((unsigned int)v.y) << 16);
    a[3] += __uint_as_float(((unsigned int)v.y) & 0xFFFF0000u);
    a[4] += __uint_as_float(((unsigned int)v.z) << 16);
    a[5] += __uint_as_float(((unsigned int)v.z) & 0xFFFF0000u);
    a[6] += __uint_as_float(((unsigned int)v.w) << 16);
    a[7] += __uint_as_float(((unsigned int)v.w) & 0xFFFF0000u);
}
__device__ __forceinline__ unsigned int pack2(float x, float y) {
    return (unsigned int)f2bf(x) | ((unsigned int)f2bf(y) << 16);
}

// ---------------- CSR build (fixed-capacity buckets) ----------------

__global__ __launch_bounds__(256) void partition_kernel(const int* __restrict__ src,
                                                        const int* __restrict__ dst, int E,
                                                        int* __restrict__ bcur,
                                                        unsigned int* __restrict__ pairs,
                                                        int B) {
    __shared__ int h[1024];
    __shared__ int rankbase[1024];
    int t = threadIdx.x;
    int tile0 = blockIdx.x * PART_TILE;
    for (int i = t; i < B; i += 256) h[i] = 0;
    __syncthreads();

    int bk[16];
    int rk[16];
    unsigned int pk[16];
#pragma unroll
    for (int j = 0; j < 16; ++j) {
        int idx = tile0 + j * 256 + t;
        bk[j] = -1;
        if (idx < E) {
            int d = dst[idx];
            int s = src[idx];
            bk[j] = d >> NBS;
            pk[j] = ((unsigned int)(d & (NPB - 1)) << 23) | (unsigned int)s;
            rk[j] = atomicAdd(&h[bk[j]], 1);
        }
    }
    __syncthreads();
    for (int i = t; i < B; i += 256) rankbase[i] = h[i] ? atomicAdd(&bcur[i], h[i]) : 0;
    __syncthreads();
#pragma unroll
    for (int j = 0; j < 16; ++j)
        if (bk[j] >= 0) pairs[rankbase[bk[j]] + rk[j]] = pk[j];
}

// per-bucket: hist + in-bucket scan -> rps/rpe/dinv + scatter -> col
__global__ __launch_bounds__(256) void bucket_finalize(const unsigned int* __restrict__ pairs,
                                                       const int* __restrict__ bcur,
                                                       int* __restrict__ rps,
                                                       int* __restrict__ rpe,
                                                       float* __restrict__ dinv,
                                                       int* __restrict__ col, int N) {
    __shared__ int c[NPB];
    __shared__ int sa[NPB];
    __shared__ int sb[NPB];
    __shared__ unsigned int stage[BCAP];
    int b = blockIdx.x;
    int s = b * BCAP;
    int cnt = bcur[b] - s;
    if (threadIdx.x < NPB) c[threadIdx.x] = 0;
    __syncthreads();
    for (int i = threadIdx.x; i < cnt; i += 256) {
        unsigned int p = pairs[s + i];
        stage[i] = p;
        atomicAdd(&c[p >> 23], 1);
    }
    __syncthreads();
    if (threadIdx.x < NPB) sa[threadIdx.x] = c[threadIdx.x];
    __syncthreads();
    int* pin = sa;
    int* pout = sb;
    for (int off = 1; off < NPB; off <<= 1) {
        if (threadIdx.x < NPB)
            pout[threadIdx.x] = pin[threadIdx.x] + ((threadIdx.x >= (unsigned)off) ? pin[threadIdx.x - off] : 0);
        __syncthreads();
        int* tmp = pin; pin = pout; pout = tmp;
    }
    int base = b << NBS;
    if (threadIdx.x < NPB) {
        int i = threadIdx.x;
        int excl = s + pin[i] - c[i];
        pout[i] = excl;
        int node = base + i;
        if (node < N) {
            rps[node] = excl;
            rpe[node] = excl + c[i];
            dinv[node] = rsqrtf((float)c[i] + 1.0f);
        }
    }
    __syncthreads();
    for (int i = threadIdx.x; i < cnt; i += 256) {
        unsigned int p = stage[i];
        int dL = (int)(p >> 23);
        int pos = atomicAdd(&pout[dL], 1);
        col[pos] = (int)(p & 0x7FFFFFu);
    }
}

// ---------------- weight prep + bcur init + ps zero (one launch) ----------------

__global__ void wconv_kernel(const float* __restrict__ W1, const float* __restrict__ W2,
                             unsigned short* __restrict__ Wt1, unsigned short* __restrict__ Wt2,
                             int* __restrict__ bcur, int B,
                             float* __restrict__ ps, int psn) {
    const float* W = (blockIdx.x & 128) ? W2 : W1;
    unsigned short* Wt = (blockIdx.x & 128) ? Wt2 : Wt1;
    int n = blockIdx.x & 127;
    int k = threadIdx.x;
    Wt[n * 128 + k] = f2bf(W[k * 128 + n]);
    int tid = blockIdx.x * 128 + threadIdx.x;
    if (tid < B) bcur[tid] = tid * BCAP;
    for (int i = tid; i < psn; i += 256 * 128) ps[i] = 0.f;
}

// ---------------- GEMM (MFMA) ----------------

// 64 rows/block, 4 waves x 16 rows. Wt (128x128 bf16) staged+swizzled in LDS.
template <bool A_F32>
__global__ __launch_bounds__(256) void gemm_mfma(const void* __restrict__ Ap,
                                                 const unsigned short* __restrict__ Wt,
                                                 const float* __restrict__ dinv,
                                                 unsigned short* __restrict__ C, int M) {
    __shared__ unsigned char lds[32768];
    int t = threadIdx.x;
#pragma unroll
    for (int i = 0; i < 8; ++i) {
        int c = t + i * 256;
        int row = c >> 4;
        int b = (c & 15) << 4;
        int4 v = ((const int4*)Wt)[c];
        *(int4*)&lds[row * 256 + (b ^ ((row & 7) << 4))] = v;
    }

    int lane = t & 63;
    int wv = t >> 6;
    int r0 = blockIdx.x * 64 + wv * 16;
    int l15 = lane & 15;
    int kg = lane >> 4;

    short8 af[4];
    {
        int row = r0 + l15;
        row = row < M ? row : M - 1;
#pragma unroll
        for (int kk = 0; kk < 4; ++kk) {
            size_t eoff = (size_t)row * 128 + kk * 32 + kg * 8;
            if constexpr (A_F32) {
                const float* A = (const float*)Ap;
                f32x4 v0 = __builtin_nontemporal_load((const f32x4*)(A + eoff));
                f32x4 v1 = __builtin_nontemporal_load((const f32x4*)(A + eoff + 4));
                af[kk] = pack_bf8(v0, v1);
            } else {
                af[kk] = *(const short8*)((const unsigned short*)Ap + eoff);
            }
        }
    }
    __syncthreads();

    f32x4 acc[8];
#pragma unroll
    for (int cf = 0; cf < 8; ++cf) acc[cf] = (f32x4)(0.f);

#pragma unroll
    for (int cf = 0; cf < 8; ++cf) {
        short8 bfr[4];
#pragma unroll
        for (int kk = 0; kk < 4; ++kk) {
            int brow = cf * 16 + l15;
            int bb = kk * 64 + kg * 16;
            bfr[kk] = *(const short8*)&lds[brow * 256 + (bb ^ ((brow & 7) << 4))];
        }
#pragma unroll
        for (int kk = 0; kk < 4; ++kk)
            acc[cf] = __builtin_amdgcn_mfma_f32_16x16x32_bf16(af[kk], bfr[kk], acc[cf], 0, 0, 0);
    }

#pragma unroll
    for (int r = 0; r < 4; ++r) {
        int row = r0 + kg * 4 + r;
        if (row < M) {
            float dv = dinv[row];
#pragma unroll
            for (int cf = 0; cf < 8; ++cf)
                C[(size_t)row * 128 + cf * 16 + l15] = f2bf(acc[cf][r] * dv);
        }
    }
}

// ---------------- aggregation (+ fused pool for layer 2) ----------------

// 16 lanes/node (dwordx4 gathers), 16 nodes/block, natural node order.
template <bool FUSE_POOL>
__global__ __launch_bounds__(256) void agg_q16(const unsigned short* __restrict__ hs,
                                               const float* __restrict__ dinv,
                                               const int* __restrict__ rps,
                                               const int* __restrict__ rpe,
                                               const int* __restrict__ col,
                                               const float* __restrict__ bias,
                                               const int* __restrict__ batch,
                                               unsigned short* __restrict__ out,
                                               float* __restrict__ ps, int N) {
    int slot = threadIdx.x >> 4;
    int g = blockIdx.x * 16 + slot;
    int l = threadIdx.x & 15;
    bool valid = (g < N);
    if (!FUSE_POOL && !valid) return;

    float a[8];
#pragma unroll
    for (int k = 0; k < 8; ++k) a[k] = 0.f;

    if (valid) {
        const int4* h4 = (const int4*)hs;
        {
            int4 sv = h4[(size_t)g * 16 + l];  // self (hs_i)
            acc8(sv, a);
        }
        int e = rps[g], end = rpe[g];
        for (; e + 7 < end; e += 8) {
            int j0 = col[e + 0], j1 = col[e + 1], j2 = col[e + 2], j3 = col[e + 3];
            int j4 = col[e + 4], j5 = col[e + 5], j6 = col[e + 6], j7 = col[e + 7];
            int4 v0 = h4[(size_t)j0 * 16 + l];
            int4 v1 = h4[(size_t)j1 * 16 + l];
            int4 v2 = h4[(size_t)j2 * 16 + l];
            int4 v3 = h4[(size_t)j3 * 16 + l];
            int4 v4 = h4[(size_t)j4 * 16 + l];
            int4 v5 = h4[(size_t)j5 * 16 + l];
            int4 v6 = h4[(size_t)j6 * 16 + l];
            int4 v7 = h4[(size_t)j7 * 16 + l];
            acc8(v0, a); acc8(v1, a); acc8(v2, a); acc8(v3, a);
            acc8(v4, a); acc8(v5, a); acc8(v6, a); acc8(v7, a);
        }
        for (; e + 1 < end; e += 2) {
            int j0 = col[e], j1 = col[e + 1];
            int4 v0 = h4[(size_t)j0 * 16 + l];
            int4 v1 = h4[(size_t)j1 * 16 + l];
            acc8(v0, a); acc8(v1, a);
        }
        if (e < end) {
            int j = col[e];
            acc8(h4[(size_t)j * 16 + l], a);
        }

        float dv = dinv[g];
        float4 b0 = ((const float4*)bias)[l * 2];
        float4 b1 = ((const float4*)bias)[l * 2 + 1];
        a[0] = fmaxf(fmaf(a[0], dv, b0.x), 0.f);
        a[1] = fmaxf(fmaf(a[1], dv, b0.y), 0.f);
        a[2] = fmaxf(fmaf(a[2], dv, b0.z), 0.f);
        a[3] = fmaxf(fmaf(a[3], dv, b0.w), 0.f);
        a[4] = fmaxf(fmaf(a[4], dv, b1.x), 0.f);
        a[5] = fmaxf(fmaf(a[5], dv, b1.y), 0.f);
        a[6] = fmaxf(fmaf(a[6], dv, b1.z), 0.f);
        a[7] = fmaxf(fmaf(a[7], dv, b1.w), 0.f);
    }

    if constexpr (FUSE_POOL) {
        __shared__ float sacc[16][128];
        __shared__ int sbatch[16];
        if (l == 0) sbatch[slot] = valid ? batch[g] : -1;
#pragma unroll
        for (int k = 0; k < 8; ++k) sacc[slot][l * 8 + k] = a[k];
        __syncthreads();
        if (threadIdx.x < 128) {
            int f = threadIdx.x;
            float run = 0.f;
            int curg = sbatch[0];
#pragma unroll
            for (int s2 = 0; s2 < 16; ++s2) {
                int gg = sbatch[s2];
                if (gg < 0) break;
                if (gg != curg) {
                    atomicAdd(&ps[curg * 128 + f], run);
                    run = 0.f;
                    curg = gg;
                }
                run += sacc[s2][f];
            }
            if (curg >= 0) atomicAdd(&ps[curg * 128 + f], run);
        }
    } else {
        int4 o;
        o.x = (int)pack2(a[0], a[1]);
        o.y = (int)pack2(a[2], a[3]);
        o.z = (int)pack2(a[4], a[5]);
        o.w = (int)pack2(a[6], a[7]);
        ((int4*)out)[(size_t)g * 16 + l] = o;
    }
}

// out[g] = (ps[g] . Wlin) / cnt(g) + blin; cnt via binary search on sorted batch
__global__ __launch_bounds__(256) void final_kernel(const float* __restrict__ ps,
                                                    const int* __restrict__ batch, int N,
                                                    const float* __restrict__ Wlin,
                                                    const float* __restrict__ blin,
                                                    float* __restrict__ out, int G) {
    int g = (int)((blockIdx.x * 256 + threadIdx.x) >> 6);
    int lane = threadIdx.x & 63;
    if (g >= G) return;
    float2 s = ((const float2*)ps)[g * 64 + lane];
    float2 w = ((const float2*)Wlin)[lane];
    float v = s.x * w.x + s.y * w.y;
#pragma unroll
    for (int off = 32; off > 0; off >>= 1) v += __shfl_down(v, off);
    if (lane == 0) {
        int lo = 0, hi = N;
        while (lo < hi) { int m = (lo + hi) >> 1; if (batch[m] < g) lo = m + 1; else hi = m; }
        int lb = lo;
        hi = N;
        while (lo < hi) { int m = (lo + hi) >> 1; if (batch[m] <= g) lo = m + 1; else hi = m; }
        float c = (float)max(lo - lb, 1);
        out[g] = v / c + blin[0];
    }
}

extern "C" void kernel_launch(void* const* d_in, const int* in_sizes, int n_in,
                              void* d_out, int out_size, void* d_ws, size_t ws_size,
                              hipStream_t stream) {
    const float* x    = (const float*)d_in[0];
    const float* W1   = (const float*)d_in[1];
    const float* b1   = (const float*)d_in[2];
    const float* W2   = (const float*)d_in[3];
    const float* b2   = (const float*)d_in[4];
    const float* Wlin = (const float*)d_in[5];
    const float* blin = (const float*)d_in[6];
    const int*   ei   = (const int*)d_in[7];   // [2, E]
    const int*   batch= (const int*)d_in[8];   // [N]

    const int N = in_sizes[0] / 128;
    const int E = in_sizes[7] / 2;
    const int G = out_size;
    const int B = (N + NPB - 1) >> NBS;

    const int* srcp = ei;
    const int* dstp = ei + E;

    char* w = (char*)d_ws;
    size_t off = 0;
    auto carve = [&](size_t bytes) {
        size_t o = off;
        off = (off + bytes + 255) & ~(size_t)255;
        return (void*)(w + o);
    };
    unsigned short* bufA = (unsigned short*)carve((size_t)N * 128 * 2);
    unsigned short* bufB = (unsigned short*)carve((size_t)N * 128 * 2);
    float* dinv = (float*)carve((size_t)N * 4);
    int*   rps  = (int*)carve((size_t)N * 4);
    int*   rpe  = (int*)carve((size_t)N * 4);
    int*   col  = (int*)carve((size_t)B * BCAP * 4);
    unsigned int* pairs = (unsigned int*)carve((size_t)B * BCAP * 4);
    int*   bcur = (int*)carve((size_t)(B + 1) * 4);
    unsigned short* Wt1 = (unsigned short*)carve(128 * 128 * 2);
    unsigned short* Wt2 = (unsigned short*)carve(128 * 128 * 2);
    float* ps   = (float*)carve((size_t)G * 128 * 4);
    (void)ws_size;

    const int ntiles = (E + PART_TILE - 1) / PART_TILE;

    // weight prep + bcur init + ps zero (must precede partition & agg2)
    wconv_kernel<<<256, 128, 0, stream>>>(W1, W2, Wt1, Wt2, bcur, B, ps, G * 128);

    // CSR build (fixed-capacity buckets; no count/scan passes)
    partition_kernel<<<ntiles, 256, 0, stream>>>(srcp, dstp, E, bcur, pairs, B);
    bucket_finalize<<<B, 256, 0, stream>>>(pairs, bcur, rps, rpe, dinv, col, N);

    const int gemm_grid = (N + 63) / 64;
    const int agg_grid  = (N + 15) / 16;

    // layer 1
    gemm_mfma<true><<<gemm_grid, 256, 0, stream>>>(x, Wt1, dinv, bufA, N);
    agg_q16<false><<<agg_grid, 256, 0, stream>>>(bufA, dinv, rps, rpe, col, b1, batch, bufB, ps, N);
    // layer 2 (+ fused mean-pool accumulation)
    gemm_mfma<false><<<gemm_grid, 256, 0, stream>>>(bufB, Wt2, dinv, bufA, N);
    agg_q16<true><<<agg_grid, 256, 0, stream>>>(bufA, dinv, rps, rpe, col, b2, batch, bufB, ps, N);

    // head
    final_kernel<<<(G * 64 + 255) / 256, 256, 0, stream>>>(ps, batch, N, Wlin, blin,
                                                           (float*)d_out, G);
}